// Round 11
// baseline (1374.706 us; speedup 1.0000x reference)
//
#include <hip/hip_runtime.h>

#define BB 64
#define TT 1024
#define DD 256
#define HH 256
#define CH 8             // timesteps per LDS chunk
#define NCH (TT / CH)    // 128 chunks

typedef float vf4 __attribute__((ext_vector_type(4)));
typedef float f32x4 __attribute__((ext_vector_type(4)));
typedef short bf16x8 __attribute__((ext_vector_type(8)));   // 8 bf16 = 4 VGPRs

#define LD4(p) (*(const vf4*)(p))

// tanh(x) = 1 - 2/(e^{2x}+1); saturates correctly for large |x|.
__device__ __forceinline__ float fast_tanh(float x) {
    float e = __expf(2.0f * x);
    return 1.0f - 2.0f / (e + 1.0f);
}

// fp32 -> bf16 round-to-nearest-even (returns the 16-bit pattern).
__device__ __forceinline__ unsigned bf16rne(float f) {
    unsigned u = __float_as_uint(f);
    return (u + 0x7FFFu + ((u >> 16) & 1u)) >> 16;
}

// NOTE: macro params must NOT be named x/y/z/w (component-accessor capture).
#define FMR(rr, bb, ss)                   \
    rr.x = fmaf((ss), (bb).x, rr.x);      \
    rr.y = fmaf((ss), (bb).y, rr.y);      \
    rr.z = fmaf((ss), (bb).z, rr.z);      \
    rr.w = fmaf((ss), (bb).w, rr.w)

// ---------------------------------------------------------------------------
// Phase 1 (unchanged, ~160 us): xp = x * W_ih^T + b_ih, tiled GEMM.
// ---------------------------------------------------------------------------
#define BKb 32
#define LDP 132

__global__ __attribute__((amdgpu_flat_work_group_size(256, 256),
                          amdgpu_waves_per_eu(4, 4)))
void xproj_kernel(const float* __restrict__ x, const float* __restrict__ W_ih,
                  const float* __restrict__ b_ih, float* __restrict__ xp)
{
    __shared__ float As[BKb][LDP];
    __shared__ float Bs[BKb][LDP];

    const int tid = threadIdx.x;
    const int nb = blockIdx.x & 1;
    const int mb = blockIdx.x >> 1;
    const int m0 = mb * 128;
    const int n0 = nb * 128;

    const int sr = tid >> 3;
    const int sk = (tid & 7) * 4;

    const int tx = tid & 15;
    const int ty = tid >> 4;
    const int ma = ty * 4, mh = 64 + ty * 4;
    const int na = tx * 4, nh = 64 + tx * 4;

    vf4 ra0 = 0, ra1 = 0, ra2 = 0, ra3 = 0, ra4 = 0, ra5 = 0, ra6 = 0, ra7 = 0;
    vf4 rb0 = 0, rb1 = 0, rb2 = 0, rb3 = 0, rb4 = 0, rb5 = 0, rb6 = 0, rb7 = 0;

    for (int k0 = 0; k0 < DD; k0 += BKb) {
        #pragma unroll
        for (int g = 0; g < 4; ++g) {
            const int r = sr + g * 32;
            const vf4 v = LD4(x + (size_t)(m0 + r) * DD + k0 + sk);
            As[sk + 0][r] = v.x; As[sk + 1][r] = v.y;
            As[sk + 2][r] = v.z; As[sk + 3][r] = v.w;
        }
        #pragma unroll
        for (int g = 0; g < 4; ++g) {
            const int n = sr + g * 32;
            const vf4 v = LD4(W_ih + (size_t)(n0 + n) * DD + k0 + sk);
            Bs[sk + 0][n] = v.x; Bs[sk + 1][n] = v.y;
            Bs[sk + 2][n] = v.z; Bs[sk + 3][n] = v.w;
        }
        __syncthreads();

        #pragma unroll
        for (int kk = 0; kk < BKb; ++kk) {
            const vf4 alo = LD4(&As[kk][ma]);
            const vf4 ahi = LD4(&As[kk][mh]);
            const vf4 bl  = LD4(&Bs[kk][na]);
            const vf4 bh  = LD4(&Bs[kk][nh]);
            FMR(ra0, bl, alo.x); FMR(rb0, bh, alo.x);
            FMR(ra1, bl, alo.y); FMR(rb1, bh, alo.y);
            FMR(ra2, bl, alo.z); FMR(rb2, bh, alo.z);
            FMR(ra3, bl, alo.w); FMR(rb3, bh, alo.w);
            FMR(ra4, bl, ahi.x); FMR(rb4, bh, ahi.x);
            FMR(ra5, bl, ahi.y); FMR(rb5, bh, ahi.y);
            FMR(ra6, bl, ahi.z); FMR(rb6, bh, ahi.z);
            FMR(ra7, bl, ahi.w); FMR(rb7, bh, ahi.w);
        }
        __syncthreads();
    }

    const vf4 bia = LD4(b_ih + n0 + na);
    const vf4 bib = LD4(b_ih + n0 + nh);

    #define STORE_ROW(m, rA, rB)                                   \
        {                                                          \
            float* outp = xp + (size_t)(m0 + (m)) * HH + n0;       \
            *(vf4*)(outp + na) = rA + bia;                         \
            *(vf4*)(outp + nh) = rB + bib;                         \
        }
    STORE_ROW(ma + 0, ra0, rb0); STORE_ROW(ma + 1, ra1, rb1);
    STORE_ROW(ma + 2, ra2, rb2); STORE_ROW(ma + 3, ra3, rb3);
    STORE_ROW(mh + 0, ra4, rb4); STORE_ROW(mh + 1, ra5, rb5);
    STORE_ROW(mh + 2, ra6, rb6); STORE_ROW(mh + 3, ra7, rb7);
    #undef STORE_ROW
}

// ---------------------------------------------------------------------------
// Phase 2: recurrence via MFMA (R12 structure, LDS fixed). One WG per batch
// (64 WGs, 512 thr, 8 waves; wave w owns N-tiles {2w, 2w+1}).
// R12 post-mortem: 3.35e7 bank conflicts (A-read at HSTR=264 => bank =
// 4*((r+g)%8): 8-way) + 8 waves redundantly reading the full 16-row A tile
// (131 KB/step through a 128 B/cyc pipe) made LDS the step bottleneck.
// FIX (structural): A rows 1-15 are PERMANENTLY ZERO (M-padding). In the
// 16x16x32 A-fragment layout, only lanes with (lane&15)==0 hold row-0 data.
// So only those 4 lanes/wave read h from LDS; all other lanes use a zero
// fragment. A-LDS traffic drops 16x, conflicts vanish, H storage shrinks
// to row 0 only (2 splits x 2 ping x 256 shorts = 2 KB).
// Also: accumulators split into 3 independent chains per N-tile (one per
// bf16 product, summed in epilogue): dependent-MFMA chain 24 -> 8.
// Precision: fp32 via bf16 3-product split (h1w1 + h2w1 + h1w2), validated
// in R12 (absmax identical to exact-fp32 rounds).
// ---------------------------------------------------------------------------
__global__ __attribute__((amdgpu_flat_work_group_size(512, 512),
                          amdgpu_waves_per_eu(2, 2)))
void rnn_kernel(const float* __restrict__ W_hh, const float* __restrict__ b_hh,
                const float* __restrict__ xpin, float* __restrict__ hout)
{
    const int tid  = threadIdx.x;
    const int lane = tid & 63;
    const int wid  = tid >> 6;        // 0..7: wave => N-tiles {2w, 2w+1}
    const int rrow = lane & 15;       // A row / B col / D col
    const int kgrp = lane >> 4;       // 0..3: k-group
    const int b    = blockIdx.x;

    __shared__ __align__(16) short Hs[2][2][HH];        // [ping][split][n]: 2 KB
    __shared__ __align__(16) float xchk[2][CH * HH];    // 16 KB
    __shared__ __align__(16) float obuf[CH * HH];       //  8 KB   (26 KB total)

    // ---- W fragments: [nt-local][split][kk] = 32 x bf16x8 -> AGPR-parked,
    // consumed directly by MFMA (the only AGPR-sourcing instruction class).
    bf16x8 wf[2][2][8];
    #pragma unroll
    for (int t = 0; t < 2; ++t) {
        const int n = (wid * 2 + t) * 16 + rrow;
        #pragma unroll
        for (int kk = 0; kk < 8; ++kk) {
            const int k0 = kk * 32 + kgrp * 8;
            const float* wp = W_hh + (size_t)n * HH + k0;
            bf16x8 s1, s2;
            #pragma unroll
            for (int j = 0; j < 8; ++j) {
                const float f = wp[j];
                const unsigned r1 = bf16rne(f);
                const float f1 = __uint_as_float(r1 << 16);
                const unsigned r2 = bf16rne(f - f1);
                s1[j] = (short)r1;
                s2[j] = (short)r2;
            }
            wf[t][0][kk] = s1;
            wf[t][1][kk] = s2;
        }
    }
    const float bias0 = b_hh[wid * 32 + rrow];
    const float bias1 = b_hh[wid * 32 + 16 + rrow];

    const float* xbase = xpin + (size_t)b * TT * HH;
    float*       obase = hout + (size_t)b * TT * HH;

    // ---- prologue: zero H (h_0 = 0), stage xp chunk 0, prefetch chunk 1 ----
    vf4 rpf = LD4(xbase + tid * 4);               // chunk 0 (2048 floats)
    if (tid < 512) {                              // 2*2*256 shorts = 512 ints
        ((int*)Hs)[tid] = 0;
    }
    *(vf4*)&xchk[0][tid * 4] = rpf;               // (compiler inserts vmcnt wait)
    rpf = LD4(xbase + CH * HH + tid * 4);         // chunk 1, stays in flight
    __syncthreads();

    const bf16x8 zfrag = {0, 0, 0, 0, 0, 0, 0, 0};

    for (int ci = 0; ci < NCH; ++ci) {
        const int cb = ci & 1;
        const float* xc = &xchk[cb][0];

        #pragma unroll 2
        for (int s = 0; s < CH; ++s) {
            // ---- A fragments: only rrow==0 lanes hold real data ----
            bf16x8 af1[8], af2[8];
            #pragma unroll
            for (int kk = 0; kk < 8; ++kk) { af1[kk] = zfrag; af2[kk] = zfrag; }
            if (rrow == 0) {
                const short* h1p = &Hs[s & 1][0][kgrp * 8];
                const short* h2p = &Hs[s & 1][1][kgrp * 8];
                #pragma unroll
                for (int kk = 0; kk < 8; ++kk) {
                    af1[kk] = *(const bf16x8*)&h1p[kk * 32];
                    af2[kk] = *(const bf16x8*)&h2p[kk * 32];
                }
            }

            // ---- 6 independent MFMA chains (2 N-tiles x 3 products) ----
            f32x4 aA0 = {0.f, 0.f, 0.f, 0.f}, aA1 = aA0, aA2 = aA0;
            f32x4 aB0 = aA0, aB1 = aA0, aB2 = aA0;
            #pragma unroll
            for (int kk = 0; kk < 8; ++kk) {
                aA0 = __builtin_amdgcn_mfma_f32_16x16x32_bf16(af1[kk], wf[0][0][kk], aA0, 0, 0, 0);
                aB0 = __builtin_amdgcn_mfma_f32_16x16x32_bf16(af1[kk], wf[1][0][kk], aB0, 0, 0, 0);
                aA1 = __builtin_amdgcn_mfma_f32_16x16x32_bf16(af2[kk], wf[0][0][kk], aA1, 0, 0, 0);
                aB1 = __builtin_amdgcn_mfma_f32_16x16x32_bf16(af2[kk], wf[1][0][kk], aB1, 0, 0, 0);
                aA2 = __builtin_amdgcn_mfma_f32_16x16x32_bf16(af1[kk], wf[0][1][kk], aA2, 0, 0, 0);
                aB2 = __builtin_amdgcn_mfma_f32_16x16x32_bf16(af1[kk], wf[1][1][kk], aB2, 0, 0, 0);
            }

            // Stage next xp chunk (rpf loaded ~8 steps ago; vmcnt wait free).
            if (s == CH - 1 && ci != NCH - 1) {
                *(vf4*)&xchk[cb ^ 1][tid * 4] = rpf;
            }

            // ---- epilogue: D row 0 = lanes 0-15, acc element 0 ----
            if (lane < 16) {
                #pragma unroll
                for (int t = 0; t < 2; ++t) {
                    const int n = (wid * 2 + t) * 16 + lane;
                    const float acc = t ? (aB0[0] + aB1[0] + aB2[0])
                                        : (aA0[0] + aA1[0] + aA2[0]);
                    const float v = acc + xc[s * HH + n] + (t ? bias1 : bias0);
                    const float hn = fast_tanh(v);
                    const unsigned r1 = bf16rne(hn);
                    const float h1f = __uint_as_float(r1 << 16);
                    const unsigned r2 = bf16rne(hn - h1f);
                    Hs[(s + 1) & 1][0][n] = (short)r1;   // h1 for next step
                    Hs[(s + 1) & 1][1][n] = (short)r2;   // h2 for next step
                    obuf[s * HH + n] = hn;               // fp32 output staging
                }
            }
            __syncthreads();
        }

        // ---- chunk boundary: flush outputs, prefetch chunk ci+2 ----
        const vf4 ov = *(const vf4*)&obuf[tid * 4];
        *(vf4*)(obase + (size_t)ci * CH * HH + tid * 4) = ov;
        if (ci + 2 < NCH) {
            rpf = LD4(xbase + (size_t)(ci + 2) * CH * HH + tid * 4);
        }
        // obuf is single-buffered: barrier so no wave starts writing the next
        // chunk's obuf before all waves finished the flush read.
        __syncthreads();
    }
}

extern "C" void kernel_launch(void* const* d_in, const int* in_sizes, int n_in,
                              void* d_out, int out_size, void* d_ws, size_t ws_size,
                              hipStream_t stream) {
    const float* x    = (const float*)d_in[0];
    const float* W_ih = (const float*)d_in[1];
    const float* W_hh = (const float*)d_in[2];
    const float* b_ih = (const float*)d_in[3];
    const float* b_hh = (const float*)d_in[4];
    float* out = (float*)d_out;

    const size_t xp_bytes = (size_t)BB * TT * HH * sizeof(float);   // 64 MiB
    // Aliased fallback stays correct: xp chunk k is loaded (2 chunks ahead)
    // strictly before out chunk k is flushed.
    float* xp = (ws_size >= xp_bytes) ? (float*)d_ws : out;

    xproj_kernel<<<dim3(512 * 2), dim3(256), 0, stream>>>(x, W_ih, b_ih, xp);
    rnn_kernel<<<dim3(BB), dim3(512), 0, stream>>>(W_hh, b_hh, xp, out);
}

// Round 12
// 839.718 us; speedup vs baseline: 1.6371x; 1.6371x over previous
//
#include <hip/hip_runtime.h>

#define BB 64
#define TT 1024
#define DD 256
#define HH 256
#define CH 8             // timesteps per LDS chunk
#define NCH (TT / CH)    // 128 chunks

typedef float vf4 __attribute__((ext_vector_type(4)));
typedef float vf2 __attribute__((ext_vector_type(2)));
typedef float f32x4 __attribute__((ext_vector_type(4)));
typedef short bf16x8 __attribute__((ext_vector_type(8)));   // 8 bf16 = 4 VGPRs
struct alignas(16) v2x2 { vf2 lo, hi; };   // one 16-B load, two pk-operands

#define LD4(p) (*(const vf4*)(p))
#define LDW(p) (*(const v2x2*)(p))

// tanh(x) = 1 - 2/(e^{2x}+1); saturates correctly for large |x|.
__device__ __forceinline__ float fast_tanh(float x) {
    float e = __expf(2.0f * x);
    return 1.0f - 2.0f / (e + 1.0f);
}

// fp32 -> bf16 round-to-nearest-even (returns the 16-bit pattern).
__device__ __forceinline__ unsigned bf16rne(float f) {
    unsigned u = __float_as_uint(f);
    return (u + 0x7FFFu + ((u >> 16) & 1u)) >> 16;
}

// float2 FMA: selects v_pk_fma_f32 on gfx950 (exact fp32, 2x rate).
#define PKFMA(acc, aa, bb) acc = __builtin_elementwise_fma((aa), (bb), (acc))

// dst = src + dpp_shuffle(src). VALU-pipe cross-lane (no LDS traffic).
// CTRL: 0xB1 quad_perm xor1, 0x4E quad_perm xor2, 0x124 row_ror:4, 0x128 row_ror:8.
#define DPPADD(dst, src, CTRL) {                                                   \
    int _di = __builtin_amdgcn_update_dpp(0, __float_as_int(src), CTRL, 0xF, 0xF, true); \
    dst = (src) + __int_as_float(_di); }

// ---------------------------------------------------------------------------
// Phase 1 REWRITTEN: xp = x * W_ih^T + b_ih via MFMA 16x16x32 bf16, 3-product
// split (x=a1+a2, w=b1+b2; D = a1b1 + a2b1 + a1b2, fp32 accumulate; omitted
// a2b2 ~ 1e-6 of xp scale). Rationale: old fp32-VALU tile GEMM ran ~160us at
// 54 TF (no fp32 MFMA on CDNA4); the matrix pipe does this GEMM's 1.57M
// MFMAs in ~12us of pipe time. M-util is FULL here (M=16 of real rows), vs
// the 1/16-wasted recurrence MFMA (R12/R13 lesson: per-SIMD MFMA cost is
// ~19.4cyc, so the recurrence's 96 MFMA/SIMD/step = 1860cyc floor > GEMV).
// Fragment layouts validated on-device by R12/R13 (B: col=lane&15,
// k=(lane>>4)*8+j; D: col=lane&15, row=(lane>>4)*4+reg).
// Block: 256 thr (4 waves), M=16 rows, wave w owns N cols [64w, 64w+64).
// No LDS, no barriers. Grid = 65536/16 = 4096 blocks.
// ---------------------------------------------------------------------------
__global__ __launch_bounds__(256)
void xproj_mfma(const float* __restrict__ x, const float* __restrict__ W_ih,
                const float* __restrict__ b_ih, float* __restrict__ xp)
{
    const int tid  = threadIdx.x;
    const int lane = tid & 63;
    const int wv   = tid >> 6;         // 0..3: wave -> N range [64*wv, 64*wv+64)
    const int rrow = lane & 15;        // A row / B col / D col
    const int kgrp = lane >> 4;        // 0..3: k-group
    const size_t m0 = (size_t)blockIdx.x * 16;

    // ---- A fragments: x rows m0..m0+15, split into bf16 hi/lo ----
    bf16x8 xa1[8], xa2[8];
    const float* xr = x + (m0 + rrow) * DD + kgrp * 8;
    #pragma unroll
    for (int kk = 0; kk < 8; ++kk) {
        const float* p = xr + kk * 32;
        bf16x8 s1, s2;
        #pragma unroll
        for (int j = 0; j < 8; ++j) {
            const float f = p[j];
            const unsigned r1 = bf16rne(f);
            const float f1 = __uint_as_float(r1 << 16);
            const unsigned r2 = bf16rne(f - f1);
            s1[j] = (short)r1;
            s2[j] = (short)r2;
        }
        xa1[kk] = s1;
        xa2[kk] = s2;
    }

    // ---- 4 N-tiles per wave ----
    #pragma unroll
    for (int nt = 0; nt < 4; ++nt) {
        const int n0 = wv * 64 + nt * 16;
        const float* wr = W_ih + (size_t)(n0 + rrow) * DD + kgrp * 8;

        f32x4 c0 = {0.f, 0.f, 0.f, 0.f}, c1 = c0, c2 = c0;
        #pragma unroll
        for (int kk = 0; kk < 8; ++kk) {
            const float* p = wr + kk * 32;
            bf16x8 b1, b2;
            #pragma unroll
            for (int j = 0; j < 8; ++j) {
                const float f = p[j];
                const unsigned r1 = bf16rne(f);
                const float f1 = __uint_as_float(r1 << 16);
                const unsigned r2 = bf16rne(f - f1);
                b1[j] = (short)r1;
                b2[j] = (short)r2;
            }
            c0 = __builtin_amdgcn_mfma_f32_16x16x32_bf16(xa1[kk], b1, c0, 0, 0, 0);
            c1 = __builtin_amdgcn_mfma_f32_16x16x32_bf16(xa2[kk], b1, c1, 0, 0, 0);
            c2 = __builtin_amdgcn_mfma_f32_16x16x32_bf16(xa1[kk], b2, c2, 0, 0, 0);
        }

        // D: col = rrow, row = kgrp*4 + r.  xp[m0+row][n0+col] += bias[n0+col]
        const float bias = b_ih[n0 + rrow];
        #pragma unroll
        for (int r = 0; r < 4; ++r) {
            const int mrow = kgrp * 4 + r;
            xp[(m0 + mrow) * HH + n0 + rrow] = c0[r] + c1[r] + c2[r] + bias;
        }
    }
}

// ---------------------------------------------------------------------------
// Phase 2: recurrence, one WG per batch (64 WGs, 512 threads) — the proven
// 617us GEMV (R6-bench source, verbatim). G=8 outputs/lane x L=16
// k-elems/lane; chunk-staged xp/out through LDS; unroll 2; pin-once.
// Known floor analysis: ~925 cyc/SIMD issue (half of it v_accvgpr_read
// copies — allocator parks weights in AGPRs and gfx950 VALU cannot source
// AGPRs [R9 compile proof]; 4 coaxing attempts R7-R10 all failed) + ~520
// stall. MFMA recurrence is structurally worse (R12/R13: 1/16 M-util x
// 3-split = 1860+ cyc/step pipe floor).
// ---------------------------------------------------------------------------
__global__ __attribute__((amdgpu_flat_work_group_size(512, 512),
                          amdgpu_waves_per_eu(2, 2)))
void rnn_kernel(const float* __restrict__ W_hh, const float* __restrict__ b_hh,
                const float* __restrict__ xpin, float* __restrict__ hout)
{
    const int tid = threadIdx.x;
    const int jg = tid >> 4;          // 0..31: group of 8 outputs
    const int c  = tid & 15;          // 0..15: k-chunk (16 floats)
    const int j0 = jg * 8;
    const int jmine = j0 + (c & 7);   // the output this lane finalizes (writers: c<8)
    const int b = blockIdx.x;

    __shared__ float hbuf[2][16 * 20];     // h[k] at word (k>>4)*20 + (k&15)
    __shared__ float xchk[2][CH * HH];     // xp chunk double-buffer (2 x 8 KB)
    __shared__ float obuf[2][CH * HH];     // output staging double-buffer (2 x 8 KB)

    // Weights: 8 rows (j0..j0+7) x 16 cols (c*16..c*16+15) = 128 floats/lane.
    v2x2 w[8][4];
    #pragma unroll
    for (int r = 0; r < 8; ++r) {
        const float* wr = W_hh + (size_t)(j0 + r) * HH + c * 16;
        w[r][0] = LDW(wr + 0);  w[r][1] = LDW(wr + 4);
        w[r][2] = LDW(wr + 8);  w[r][3] = LDW(wr + 12);
    }
    const float bias = b_hh[jmine];

    // Pin weights ONCE (opaque redefinition => loads cannot be
    // rematerialized/sunk into the loop).
    asm volatile("" : "+v"(w[0][0].lo), "+v"(w[0][0].hi), "+v"(w[0][1].lo), "+v"(w[0][1].hi),
                      "+v"(w[0][2].lo), "+v"(w[0][2].hi), "+v"(w[0][3].lo), "+v"(w[0][3].hi),
                      "+v"(w[1][0].lo), "+v"(w[1][0].hi), "+v"(w[1][1].lo), "+v"(w[1][1].hi),
                      "+v"(w[1][2].lo), "+v"(w[1][2].hi), "+v"(w[1][3].lo), "+v"(w[1][3].hi));
    asm volatile("" : "+v"(w[2][0].lo), "+v"(w[2][0].hi), "+v"(w[2][1].lo), "+v"(w[2][1].hi),
                      "+v"(w[2][2].lo), "+v"(w[2][2].hi), "+v"(w[2][3].lo), "+v"(w[2][3].hi),
                      "+v"(w[3][0].lo), "+v"(w[3][0].hi), "+v"(w[3][1].lo), "+v"(w[3][1].hi),
                      "+v"(w[3][2].lo), "+v"(w[3][2].hi), "+v"(w[3][3].lo), "+v"(w[3][3].hi));
    asm volatile("" : "+v"(w[4][0].lo), "+v"(w[4][0].hi), "+v"(w[4][1].lo), "+v"(w[4][1].hi),
                      "+v"(w[4][2].lo), "+v"(w[4][2].hi), "+v"(w[4][3].lo), "+v"(w[4][3].hi),
                      "+v"(w[5][0].lo), "+v"(w[5][0].hi), "+v"(w[5][1].lo), "+v"(w[5][1].hi),
                      "+v"(w[5][2].lo), "+v"(w[5][2].hi), "+v"(w[5][3].lo), "+v"(w[5][3].hi));
    asm volatile("" : "+v"(w[6][0].lo), "+v"(w[6][0].hi), "+v"(w[6][1].lo), "+v"(w[6][1].hi),
                      "+v"(w[6][2].lo), "+v"(w[6][2].hi), "+v"(w[6][3].lo), "+v"(w[6][3].hi),
                      "+v"(w[7][0].lo), "+v"(w[7][0].hi), "+v"(w[7][1].lo), "+v"(w[7][1].hi),
                      "+v"(w[7][2].lo), "+v"(w[7][2].hi), "+v"(w[7][3].lo), "+v"(w[7][3].hi));

    const float* xbase = xpin + (size_t)b * TT * HH;
    float*       obase = hout + (size_t)b * TT * HH;
    const int haddr = ((jmine >> 4) * 20) + (jmine & 15);   // LDS slot for jmine

    // ---- prologue: chunk 0 into LDS, chunk 1 into registers (in flight) ----
    vf4 rpf = LD4(xbase + tid * 4);               // chunk 0 (2048 floats, 4/thread)
    if (tid < 320) hbuf[0][tid] = 0.0f;           // h_0 = 0 (pads incl.)
    *(vf4*)&xchk[0][tid * 4] = rpf;               // (compiler inserts vmcnt wait)
    rpf = LD4(xbase + CH * HH + tid * 4);         // chunk 1, stays in flight
    __syncthreads();

    for (int ci = 0; ci < NCH; ++ci) {
        const int cb = ci & 1;

        const float* xc = &xchk[cb][0];
        float*       ob = &obuf[cb][0];

        // unroll 2: hbuf[s&1] parity compile-time, pressure spike avoided.
        #pragma unroll 2
        for (int s = 0; s < CH; ++s) {
            // xp for this step: LDS read.
            const float xpb = xc[s * HH + jmine] + bias;

            const float* hc = &hbuf[s & 1][c * 20];
            const v2x2 h0 = LDW(hc + 0), h1 = LDW(hc + 4),
                       h2 = LDW(hc + 8), h3 = LDW(hc + 12);

            vf2 a0 = {0.f, 0.f}, a1 = {0.f, 0.f}, a2 = {0.f, 0.f}, a3 = {0.f, 0.f};
            vf2 a4 = {0.f, 0.f}, a5 = {0.f, 0.f}, a6 = {0.f, 0.f}, a7 = {0.f, 0.f};
            PKFMA(a0, w[0][0].lo, h0.lo); PKFMA(a0, w[0][0].hi, h0.hi);
            PKFMA(a0, w[0][1].lo, h1.lo); PKFMA(a0, w[0][1].hi, h1.hi);
            PKFMA(a0, w[0][2].lo, h2.lo); PKFMA(a0, w[0][2].hi, h2.hi);
            PKFMA(a0, w[0][3].lo, h3.lo); PKFMA(a0, w[0][3].hi, h3.hi);
            PKFMA(a1, w[1][0].lo, h0.lo); PKFMA(a1, w[1][0].hi, h0.hi);
            PKFMA(a1, w[1][1].lo, h1.lo); PKFMA(a1, w[1][1].hi, h1.hi);
            PKFMA(a1, w[1][2].lo, h2.lo); PKFMA(a1, w[1][2].hi, h2.hi);
            PKFMA(a1, w[1][3].lo, h3.lo); PKFMA(a1, w[1][3].hi, h3.hi);
            PKFMA(a2, w[2][0].lo, h0.lo); PKFMA(a2, w[2][0].hi, h0.hi);
            PKFMA(a2, w[2][1].lo, h1.lo); PKFMA(a2, w[2][1].hi, h1.hi);
            PKFMA(a2, w[2][2].lo, h2.lo); PKFMA(a2, w[2][2].hi, h2.hi);
            PKFMA(a2, w[2][3].lo, h3.lo); PKFMA(a2, w[2][3].hi, h3.hi);
            PKFMA(a3, w[3][0].lo, h0.lo); PKFMA(a3, w[3][0].hi, h0.hi);
            PKFMA(a3, w[3][1].lo, h1.lo); PKFMA(a3, w[3][1].hi, h1.hi);
            PKFMA(a3, w[3][2].lo, h2.lo); PKFMA(a3, w[3][2].hi, h2.hi);
            PKFMA(a3, w[3][3].lo, h3.lo); PKFMA(a3, w[3][3].hi, h3.hi);
            PKFMA(a4, w[4][0].lo, h0.lo); PKFMA(a4, w[4][0].hi, h0.hi);
            PKFMA(a4, w[4][1].lo, h1.lo); PKFMA(a4, w[4][1].hi, h1.hi);
            PKFMA(a4, w[4][2].lo, h2.lo); PKFMA(a4, w[4][2].hi, h2.hi);
            PKFMA(a4, w[4][3].lo, h3.lo); PKFMA(a4, w[4][3].hi, h3.hi);
            PKFMA(a5, w[5][0].lo, h0.lo); PKFMA(a5, w[5][0].hi, h0.hi);
            PKFMA(a5, w[5][1].lo, h1.lo); PKFMA(a5, w[5][1].hi, h1.hi);
            PKFMA(a5, w[5][2].lo, h2.lo); PKFMA(a5, w[5][2].hi, h2.hi);
            PKFMA(a5, w[5][3].lo, h3.lo); PKFMA(a5, w[5][3].hi, h3.hi);
            PKFMA(a6, w[6][0].lo, h0.lo); PKFMA(a6, w[6][0].hi, h0.hi);
            PKFMA(a6, w[6][1].lo, h1.lo); PKFMA(a6, w[6][1].hi, h1.hi);
            PKFMA(a6, w[6][2].lo, h2.lo); PKFMA(a6, w[6][2].hi, h2.hi);
            PKFMA(a6, w[6][3].lo, h3.lo); PKFMA(a6, w[6][3].hi, h3.hi);
            PKFMA(a7, w[7][0].lo, h0.lo); PKFMA(a7, w[7][0].hi, h0.hi);
            PKFMA(a7, w[7][1].lo, h1.lo); PKFMA(a7, w[7][1].hi, h1.hi);
            PKFMA(a7, w[7][2].lo, h2.lo); PKFMA(a7, w[7][2].hi, h2.hi);
            PKFMA(a7, w[7][3].lo, h3.lo); PKFMA(a7, w[7][3].hi, h3.hi);

            const float s0 = a0.x + a0.y, s1 = a1.x + a1.y,
                        s2 = a2.x + a2.y, s3 = a3.x + a3.y,
                        s4 = a4.x + a4.y, s5 = a5.x + a5.y,
                        s6 = a6.x + a6.y, s7 = a7.x + a7.y;

            // 16-lane reduce of 8 outputs: xor1 +sel, xor2 +sel, ror4 +sel, ror8.
            float t0, t1, t2, t3, t4, t5, t6, t7;
            DPPADD(t0, s0, 0xB1); DPPADD(t1, s1, 0xB1);
            DPPADD(t2, s2, 0xB1); DPPADD(t3, s3, 0xB1);
            DPPADD(t4, s4, 0xB1); DPPADD(t5, s5, 0xB1);
            DPPADD(t6, s6, 0xB1); DPPADD(t7, s7, 0xB1);
            const float p0 = (c & 1) ? t1 : t0;
            const float p1 = (c & 1) ? t3 : t2;
            const float p2 = (c & 1) ? t5 : t4;
            const float p3 = (c & 1) ? t7 : t6;
            float u0, u1, u2, u3;
            DPPADD(u0, p0, 0x4E); DPPADD(u1, p1, 0x4E);
            DPPADD(u2, p2, 0x4E); DPPADD(u3, p3, 0x4E);
            const float v0 = (c & 2) ? u1 : u0;
            const float v1 = (c & 2) ? u3 : u2;
            float q0, q1;
            DPPADD(q0, v0, 0x124); DPPADD(q1, v1, 0x124);
            float vfin = (c & 4) ? q1 : q0;
            DPPADD(vfin, vfin, 0x128);

            // Stage next xp chunk into the other LDS buffer (once per chunk;
            // rpf was loaded ~8 steps ago, so the vmcnt wait here is free).
            if (s == CH - 1 && ci != NCH - 1) {
                *(vf4*)&xchk[cb ^ 1][tid * 4] = rpf;
            }

            const float hn = fast_tanh(vfin + xpb);
            if (c < 8) {
                hbuf[1 - (s & 1)][haddr] = hn;        // h for next step
                ob[s * HH + jmine] = hn;              // output staging (LDS)
            }
            __syncthreads();
        }

        // ---- chunk boundary: flush outputs, prefetch chunk ci+2 ----
        // obuf[cb] is complete (post-barrier); next chunk writes obuf[cb^1],
        // so the flush read cannot race.
        const vf4 ov = *(const vf4*)&obuf[cb][tid * 4];
        *(vf4*)(obase + (size_t)ci * CH * HH + tid * 4) = ov;
        if (ci + 2 < NCH) {
            rpf = LD4(xbase + (size_t)(ci + 2) * CH * HH + tid * 4);
        }
        // These globals drain at the next chunk's first barrier — once per
        // 8 steps, overlapped with step-0 compute (~50 cyc/step amortized).
    }
}

extern "C" void kernel_launch(void* const* d_in, const int* in_sizes, int n_in,
                              void* d_out, int out_size, void* d_ws, size_t ws_size,
                              hipStream_t stream) {
    const float* x    = (const float*)d_in[0];
    const float* W_ih = (const float*)d_in[1];
    const float* W_hh = (const float*)d_in[2];
    const float* b_ih = (const float*)d_in[3];
    const float* b_hh = (const float*)d_in[4];
    float* out = (float*)d_out;

    const size_t xp_bytes = (size_t)BB * TT * HH * sizeof(float);   // 64 MiB
    // Aliased fallback stays correct: xp chunk k is loaded (2 chunks ahead)
    // strictly before out chunk k is flushed.
    float* xp = (ws_size >= xp_bytes) ? (float*)d_ws : out;

    xproj_mfma<<<dim3(BB * TT / 16), dim3(256), 0, stream>>>(x, W_ih, b_ih, xp);
    rnn_kernel<<<dim3(BB), dim3(512), 0, stream>>>(W_hh, b_hh, xp, out);
}